// Round 6
// baseline (349.404 us; speedup 1.0000x reference)
//
#include <hip/hip_runtime.h>
#include <cstdint>
#include <cstddef>

// Problem constants
constexpr int Bc = 4;
constexpr int Tc = 4096;
constexpr int Cc = 1024;
constexpr int Hc = 16;
constexpr int Dc = 64;
constexpr int Mc = Bc * Tc;        // 16384 rows
constexpr int N1c = 3 * Cc;        // 3072
constexpr int Kc = Cc;             // 1024
constexpr int KBc = Kc / 32;       // 32 k-tiles

typedef __bf16 bf16x8 __attribute__((ext_vector_type(8)));
typedef float  f32x4  __attribute__((ext_vector_type(4)));
typedef __attribute__((address_space(1))) uint32_t gu32;
typedef __attribute__((address_space(3))) uint32_t lu32;

__device__ __forceinline__ float bf2f(unsigned short u) {
    return __uint_as_float(((unsigned)u) << 16);
}
__device__ __forceinline__ unsigned short f2bf(float f) {
    unsigned u = __float_as_uint(f);
    u += 0x7FFF + ((u >> 16) & 1);   // round-to-nearest-even (finite values)
    return (unsigned short)(u >> 16);
}

__device__ __forceinline__ void load_lds16(const void* g, void* l) {
    // wave-uniform LDS base + lane*16; per-lane global address
    __builtin_amdgcn_global_load_lds((gu32*)(uintptr_t)g, (lu32*)(uintptr_t)l, 16, 0, 0);
}

// ============ packed-fragment layout ============
// A 16(rows)x32(k) tile = 512 bf16 = 64 lanes x 8 elems, contiguous in lane order.
// lane = fq*16 + fr  (fr = row&15, fq = (k&31)>>3), elem j = k&7.
// tile index: (row>>4)*KB + (k>>5). Wave fragment load = tile_base + lane*16B
// -> one coalesced b128 (global) or one conflict-free ds_read_b128 (LDS).

// ---------------- merged prep: convert_x + both weight transposes -------------
// grid = 8192 (convert_x) + 3072 (Wqkv transpose) + 1024 (Wout transpose)
__global__ __launch_bounds__(256) void prep_kernel(
    const float* __restrict__ x,    unsigned short* __restrict__ Ap,
    const float* __restrict__ Wqkv, unsigned short* __restrict__ Wqkp,
    const float* __restrict__ Wout, unsigned short* __restrict__ Wop) {
    __shared__ float tile[32][33];
    const int bid = blockIdx.x;
    const int tid = threadIdx.x;

    if (bid < 8192) {
        // ---- convert_x body (x fp32 [M][K] -> packed bf16 fragments) ----
        const int w = tid >> 6, lane = tid & 63;
        const int t = bid * 4 + w;          // tile id = mb*KB + kb
        const int mb = t >> 5, kb = t & 31;
        const int r = lane >> 2, c = lane & 3;
        const float* src = x + (size_t)(mb * 16 + r) * Kc + kb * 32 + c * 8;
        float4 f0 = *(const float4*)src;
        float4 f1 = *(const float4*)(src + 4);
        unsigned short u[8];
        u[0] = f2bf(f0.x); u[1] = f2bf(f0.y); u[2] = f2bf(f0.z); u[3] = f2bf(f0.w);
        u[4] = f2bf(f1.x); u[5] = f2bf(f1.y); u[6] = f2bf(f1.z); u[7] = f2bf(f1.w);
        *(uint4*)(Ap + (size_t)t * 512 + (c * 16 + r) * 8) = *(uint4*)u;
        return;
    }

    // ---- W fp32 [K][N] -> packed bf16 fragments (transposed) ----
    const float* W; unsigned short* Bp; int N; int b2;
    if (bid < 8192 + 3072) { W = Wqkv; Bp = Wqkp; N = 3072; b2 = bid - 8192; }
    else                   { W = Wout; Bp = Wop;  N = 1024; b2 = bid - 11264; }
    const int NT = N >> 5;
    const int n0 = (b2 % NT) * 32, k0 = (b2 / NT) * 32;
    const int tx = tid & 31, ty = tid >> 5;
    for (int i = ty; i < 32; i += 8)
        tile[i][tx] = W[(size_t)(k0 + i) * N + n0 + tx];
    __syncthreads();
    const int t = tid;
    const int h = t >> 7, rr = t & 127, lane = rr >> 1, half = rr & 1;
    const int fq = lane >> 4, fn = lane & 15;
    unsigned short u[4];
    #pragma unroll
    for (int j = 0; j < 4; ++j)
        u[j] = f2bf(tile[fq * 8 + half * 4 + j][h * 16 + fn]);
    size_t tileIdx = (size_t)((n0 >> 4) + h) * (Kc >> 5) + (k0 >> 5);
    *(uint2*)(Bp + tileIdx * 512 + lane * 8 + half * 4) = *(uint2*)u;
}

// ---------------- LDS-staged bf16 MFMA GEMM, BK=64 -----------------------------
// Verified round-5 structure (128x128 block, 4 waves, 4 blocks/CU, BK=64,
// 32 KB LDS, 102 us). New template params:
//  VPERM: permute store addresses in the V range (col>=2048) of qkv so V is
//         stored per-row transposed (ch = g*64+d -> d*16+g). Free: the
//         epilogue stores are scalar anyway. Lets attn read V^T vectorized.
//  AROW:  A operand is ROW-MAJOR [M][K] bf16; the staging DMA gathers the
//         fragment layout via per-lane global addresses (16B/lane contiguous).
//         Used by GEMM2 so attn can emit a plain row-major output.
template <bool OUT_BF16, bool VPERM, bool AROW>
__global__ __launch_bounds__(256, 4) void lds_gemm_kernel(
    const unsigned short* __restrict__ Ap,
    const unsigned short* __restrict__ Bp,
    const float* __restrict__ bias,
    void* __restrict__ Cout,
    int M, int N, int K, int NB) {
    __shared__ unsigned short sA[16 * 512];   // [mt*2+s][512]  (s = k-subtile)
    __shared__ unsigned short sB[16 * 512];   // [nt*2+s][512]
    const int KB = K >> 5;                    // 32-wide k-tiles
    const int MB = M >> 7;
    const int id   = blockIdx.x;
    const int xcd  = id & 7;
    const int per  = id >> 3;
    const int MSTR = MB >> 3;
    const int byl  = per & 7;
    const int bx   = (per >> 3) % NB;
    const int pass = per / (8 * NB);
    const int by   = xcd * MSTR + pass * 8 + byl;

    const int w    = threadIdx.x >> 6;
    const int lane = threadIdx.x & 63;
    const int m0 = by * 128;
    const int n0 = bx * 128;
    const int wm = (w >> 1) * 64;
    const int wn = (w & 1) * 64;

    // staging: wave w owns LDS tiles {4w..4w+3} of A and of B.
    // LDS tile t -> (mt = t>>1, s = t&1); global k-tile = 2j + s.
    const unsigned short* gA[4];
    const unsigned short* gB[4];
    unsigned short* lA[4];
    unsigned short* lB[4];
    {
        const int frl = lane & 15, fql = lane >> 4;
        #pragma unroll
        for (int i = 0; i < 4; ++i) {
            const int t  = w * 4 + i;
            const int mt = t >> 1, s = t & 1;
            if (AROW)
                gA[i] = Ap + ((size_t)((by * 8 + mt) * 16 + frl)) * K + s * 32 + fql * 8;
            else
                gA[i] = Ap + ((size_t)(by * 8 + mt) * KB + s) * 512 + lane * 8;
            gB[i] = Bp + ((size_t)(bx * 8 + mt) * KB + s) * 512 + lane * 8;
            lA[i] = sA + t * 512;
            lB[i] = sB + t * 512;
        }
    }

    // fragment read pointers (linear in lane -> conflict-free ds_read_b128)
    const unsigned short* aP = sA + (wm >> 4) * 2 * 512 + lane * 8;
    const unsigned short* bP = sB + (wn >> 4) * 2 * 512 + lane * 8;

    const f32x4 zero4 = {0.f, 0.f, 0.f, 0.f};
    f32x4 acc[4][4];
    #pragma unroll
    for (int i = 0; i < 4; ++i)
        #pragma unroll
        for (int j = 0; j < 4; ++j) acc[i][j] = zero4;

    const int NIT = K >> 6;   // BK=64 iterations
    #pragma unroll 1
    for (int jt = 0; jt < NIT; ++jt) {
        #pragma unroll
        for (int i = 0; i < 4; ++i) {
            load_lds16(gA[i], lA[i]);
            load_lds16(gB[i], lB[i]);
        }
        #pragma unroll
        for (int i = 0; i < 4; ++i) { gA[i] += AROW ? 64 : 1024; gB[i] += 1024; }
        __syncthreads();   // drains DMA (vmcnt) + aligns waves

        #pragma unroll
        for (int kk = 0; kk < 2; ++kk) {
            bf16x8 af[4], bfr[4];
            #pragma unroll
            for (int mi = 0; mi < 4; ++mi)
                af[mi]  = *(const bf16x8*)(aP + (mi * 2 + kk) * 512);
            #pragma unroll
            for (int ni = 0; ni < 4; ++ni)
                bfr[ni] = *(const bf16x8*)(bP + (ni * 2 + kk) * 512);
            #pragma unroll
            for (int mi = 0; mi < 4; ++mi)
                #pragma unroll
                for (int ni = 0; ni < 4; ++ni)
                    acc[mi][ni] = __builtin_amdgcn_mfma_f32_16x16x32_bf16(
                        af[mi], bfr[ni], acc[mi][ni], 0, 0, 0);
        }
        __syncthreads();   // LDS consumed before next staging overwrites
    }

    // epilogue: D row = (lane>>4)*4 + reg, col = lane&15
    const int fr = lane & 15;
    const int fq = lane >> 4;
    #pragma unroll
    for (int mi = 0; mi < 4; ++mi) {
        #pragma unroll
        for (int ni = 0; ni < 4; ++ni) {
            int row = m0 + wm + mi * 16 + fq * 4;
            int col = n0 + wn + ni * 16 + fr;
            float bb = bias[col];
            int scol = col;
            if (VPERM && col >= 2048) {          // store V transposed per row
                int c = col - 2048;              // c = g*64 + d
                scol = 2048 + ((c & 63) << 4) + (c >> 6);   // -> d*16 + g
            }
            #pragma unroll
            for (int r = 0; r < 4; ++r) {
                float v = acc[mi][ni][r] + bb;
                if (OUT_BF16)
                    ((unsigned short*)Cout)[(size_t)(row + r) * N + scol] = f2bf(v);
                else
                    ((float*)Cout)[(size_t)(row + r) * N + scol] = v;
            }
        }
    }
}

// ---------------- per-token head-axis attention, MFMA, row-major out ----------
// One wave per token. Changes vs round-0 (verified math path kept):
//  - V arrives TRANSPOSED per row (GEMM1 VPERM): Vt[d*16+g] = V[g][d].
//    Staged to LDS with 2 coalesced b128 reads into [64][24]-stride rows;
//    each PV B-fragment is then ONE ds_read_b128 (<=2-way conflicts = free),
//    replacing 32 ~4-way-conflicted ds_read_u16 per lane.
//  - output row-major attR[token][ch]: store chunks are 32B-contiguous
//    (was 16B) and addressing VALU shrinks; GEMM2 gathers fragments via
//    per-lane global_load_lds addresses (AROW).
__global__ __launch_bounds__(256) void attn_mfma_kernel(
    const unsigned short* __restrict__ qkv,
    unsigned short* __restrict__ attR) {
    // per-token: sVt [64][24] bf16 = 3072B | sP [16][20] f32 = 1280B
    __shared__ char smem[4 * 4352];
    const int w    = threadIdx.x >> 6;
    const int lane = threadIdx.x & 63;
    const int m    = lane & 15;
    const int q    = lane >> 4;
    const int row  = blockIdx.x * 4 + w;
    unsigned short* sVt = (unsigned short*)(smem + w * 4352);
    float*          sP  = (float*)(smem + w * 4352 + 3072);

    const unsigned short* src = qkv + (size_t)row * 3072;

    bf16x8 aq0 = *(const bf16x8*)(src + m * 64 + q * 8);
    bf16x8 aq1 = *(const bf16x8*)(src + m * 64 + 32 + q * 8);
    bf16x8 bk0 = *(const bf16x8*)(src + 1024 + m * 64 + q * 8);
    bf16x8 bk1 = *(const bf16x8*)(src + 1024 + m * 64 + 32 + q * 8);

    // stage Vt rows: Vt[d*16+g]; LDS row stride 24 shorts (48B, 16B-aligned)
    #pragma unroll
    for (int t = 0; t < 2; ++t) {
        int G = t * 64 + lane;                 // 0..127, 8 shorts each
        int d = G >> 1, hf = G & 1;
        *(uint4*)(sVt + d * 24 + hf * 8) = *(const uint4*)(src + 2048 + G * 8);
    }

    f32x4 s = {0.f, 0.f, 0.f, 0.f};
    s = __builtin_amdgcn_mfma_f32_16x16x32_bf16(aq0, bk0, s, 0, 0, 0);
    s = __builtin_amdgcn_mfma_f32_16x16x32_bf16(aq1, bk1, s, 0, 0, 0);

    #pragma unroll
    for (int r = 0; r < 4; ++r) {
        float t0 = s[r] * 0.125f;
        float mx = t0;
        mx = fmaxf(mx, __shfl_xor(mx, 1));
        mx = fmaxf(mx, __shfl_xor(mx, 2));
        mx = fmaxf(mx, __shfl_xor(mx, 4));
        mx = fmaxf(mx, __shfl_xor(mx, 8));
        float e = __expf(t0 - mx);
        float su = e;
        su += __shfl_xor(su, 1);
        su += __shfl_xor(su, 2);
        su += __shfl_xor(su, 4);
        su += __shfl_xor(su, 8);
        sP[(q * 4 + r) * 20 + m] = e / su;
    }
    __syncthreads();   // publishes sVt + sP

    const float* pr = sP + m * 20 + (q & 1) * 8;
    float4 pf0 = *(const float4*)(pr);
    float4 pf1 = *(const float4*)(pr + 4);
    const bool act = (q < 2);
    union { unsigned short u[8]; bf16x8 b; } pa;
    pa.u[0] = act ? f2bf(pf0.x) : 0;
    pa.u[1] = act ? f2bf(pf0.y) : 0;
    pa.u[2] = act ? f2bf(pf0.z) : 0;
    pa.u[3] = act ? f2bf(pf0.w) : 0;
    pa.u[4] = act ? f2bf(pf1.x) : 0;
    pa.u[5] = act ? f2bf(pf1.y) : 0;
    pa.u[6] = act ? f2bf(pf1.z) : 0;
    pa.u[7] = act ? f2bf(pf1.w) : 0;

    // PV: B-fragment elem e of lane(m,q) = V[(q&1)*8+e][c4*16+m]
    //   = sVt[(c4*16+m)*24 + (q&1)*8 + e]  -> one b128 per c4
    const unsigned short* vrow = sVt + (q & 1) * 8;
    unsigned short* outp = attR + (size_t)row * 1024;
    #pragma unroll
    for (int c4 = 0; c4 < 4; ++c4) {
        bf16x8 vf = *(const bf16x8*)(vrow + (c4 * 16 + m) * 24);
        f32x4 o = {0.f, 0.f, 0.f, 0.f};
        o = __builtin_amdgcn_mfma_f32_16x16x32_bf16(pa.b, vf, o, 0, 0, 0);
        #pragma unroll
        for (int r = 0; r < 4; ++r) {
            int ch = (q * 4 + r) * 64 + c4 * 16 + m;   // h*64 + d
            outp[ch] = f2bf(o[r]);
        }
    }
}

extern "C" void kernel_launch(void* const* d_in, const int* in_sizes, int n_in,
                              void* d_out, int out_size, void* d_ws, size_t ws_size,
                              hipStream_t stream) {
    const float* x    = (const float*)d_in[0];
    const float* Wqkv = (const float*)d_in[1];
    const float* bqkv = (const float*)d_in[2];
    const float* Wout = (const float*)d_in[3];
    const float* bout = (const float*)d_in[4];
    float* out = (float*)d_out;

    // workspace: xp 32M | Wqkv_p 6M | Wout_p 2M | qkv 96M = ~136 MB
    char* ws = (char*)d_ws;
    unsigned short* xp   = (unsigned short*)ws;                 ws += (size_t)Mc * Kc * 2;
    unsigned short* Wqkp = (unsigned short*)ws;                 ws += (size_t)N1c * Kc * 2;
    unsigned short* Wop  = (unsigned short*)ws;                 ws += (size_t)Cc * Kc * 2;
    unsigned short* qkv  = (unsigned short*)ws;
    unsigned short* attR = xp;   // alias: xp dead after GEMM1 (row-major [M][1024])

    // 1) prep: x -> packed fragments; weights -> packed fragments (transposed)
    prep_kernel<<<8192 + 3072 + 1024, 256, 0, stream>>>(x, xp, Wqkv, Wqkp, Wout, Wop);
    // 2) qkv = x @ W_qkv + b_qkv (bf16 row-major out; V range stored transposed)
    lds_gemm_kernel<true, true, false><<<(N1c / 128) * (Mc / 128), 256, 0, stream>>>(
        xp, Wqkp, bqkv, qkv, Mc, N1c, Kc, N1c / 128);
    // 3) head-axis attention per token (MFMA), row-major output
    attn_mfma_kernel<<<Mc / 4, 256, 0, stream>>>(qkv, attR);
    // 4) out = att @ W_out + b_out (fp32 row-major out; A gathered row-major)
    lds_gemm_kernel<false, false, true><<<(Cc / 128) * (Mc / 128), 256, 0, stream>>>(
        attR, Wop, bout, out, Mc, Cc, Kc, Cc / 128);
}

// Round 7
// 303.297 us; speedup vs baseline: 1.1520x; 1.1520x over previous
//
#include <hip/hip_runtime.h>
#include <cstdint>
#include <cstddef>

// Problem constants
constexpr int Bc = 4;
constexpr int Tc = 4096;
constexpr int Cc = 1024;
constexpr int Hc = 16;
constexpr int Dc = 64;
constexpr int Mc = Bc * Tc;        // 16384 rows
constexpr int N1c = 3 * Cc;        // 3072
constexpr int Kc = Cc;             // 1024
constexpr int KBc = Kc / 32;       // 32 k-tiles

typedef __bf16 bf16x8 __attribute__((ext_vector_type(8)));
typedef float  f32x4  __attribute__((ext_vector_type(4)));
typedef __attribute__((address_space(1))) uint32_t gu32;
typedef __attribute__((address_space(3))) uint32_t lu32;

__device__ __forceinline__ float bf2f(unsigned short u) {
    return __uint_as_float(((unsigned)u) << 16);
}
__device__ __forceinline__ unsigned short f2bf(float f) {
    unsigned u = __float_as_uint(f);
    u += 0x7FFF + ((u >> 16) & 1);   // round-to-nearest-even (finite values)
    return (unsigned short)(u >> 16);
}

__device__ __forceinline__ void load_lds16(const void* g, void* l) {
    // wave-uniform LDS base + lane*16; per-lane global address
    __builtin_amdgcn_global_load_lds((gu32*)(uintptr_t)g, (lu32*)(uintptr_t)l, 16, 0, 0);
}

// ============ packed-fragment layout ============
// A 16(rows)x32(k) tile = 512 bf16 = 64 lanes x 8 elems, contiguous in lane order.
// lane = fq*16 + fr  (fr = row&15, fq = (k&31)>>3), elem j = k&7.
// tile index: (row>>4)*KB + (k>>5). Wave fragment load = tile_base + lane*16B
// -> one coalesced b128 (global) or one conflict-free ds_read_b128 (LDS).

// ---------------- merged prep: convert_x + both weight transposes -------------
// grid = 8192 (convert_x) + 3072 (Wqkv transpose) + 1024 (Wout transpose)
__global__ __launch_bounds__(256) void prep_kernel(
    const float* __restrict__ x,    unsigned short* __restrict__ Ap,
    const float* __restrict__ Wqkv, unsigned short* __restrict__ Wqkp,
    const float* __restrict__ Wout, unsigned short* __restrict__ Wop) {
    __shared__ float tile[32][33];
    const int bid = blockIdx.x;
    const int tid = threadIdx.x;

    if (bid < 8192) {
        // ---- convert_x body (x fp32 [M][K] -> packed bf16 fragments) ----
        const int w = tid >> 6, lane = tid & 63;
        const int t = bid * 4 + w;          // tile id = mb*KB + kb
        const int mb = t >> 5, kb = t & 31;
        const int r = lane >> 2, c = lane & 3;
        const float* src = x + (size_t)(mb * 16 + r) * Kc + kb * 32 + c * 8;
        float4 f0 = *(const float4*)src;
        float4 f1 = *(const float4*)(src + 4);
        unsigned short u[8];
        u[0] = f2bf(f0.x); u[1] = f2bf(f0.y); u[2] = f2bf(f0.z); u[3] = f2bf(f0.w);
        u[4] = f2bf(f1.x); u[5] = f2bf(f1.y); u[6] = f2bf(f1.z); u[7] = f2bf(f1.w);
        *(uint4*)(Ap + (size_t)t * 512 + (c * 16 + r) * 8) = *(uint4*)u;
        return;
    }

    // ---- W fp32 [K][N] -> packed bf16 fragments (transposed) ----
    const float* W; unsigned short* Bp; int N; int b2;
    if (bid < 8192 + 3072) { W = Wqkv; Bp = Wqkp; N = 3072; b2 = bid - 8192; }
    else                   { W = Wout; Bp = Wop;  N = 1024; b2 = bid - 11264; }
    const int NT = N >> 5;
    const int n0 = (b2 % NT) * 32, k0 = (b2 / NT) * 32;
    const int tx = tid & 31, ty = tid >> 5;
    for (int i = ty; i < 32; i += 8)
        tile[i][tx] = W[(size_t)(k0 + i) * N + n0 + tx];
    __syncthreads();
    const int t = tid;
    const int h = t >> 7, rr = t & 127, lane = rr >> 1, half = rr & 1;
    const int fq = lane >> 4, fn = lane & 15;
    unsigned short u[4];
    #pragma unroll
    for (int j = 0; j < 4; ++j)
        u[j] = f2bf(tile[fq * 8 + half * 4 + j][h * 16 + fn]);
    size_t tileIdx = (size_t)((n0 >> 4) + h) * (Kc >> 5) + (k0 >> 5);
    *(uint2*)(Bp + tileIdx * 512 + lane * 8 + half * 4) = *(uint2*)u;
}

// ---------------- LDS-staged bf16 MFMA GEMM, BK=64 (r5 verified, 102 us) -------
// 128x128 block, 4 waves, 64x64/wave, 4 blocks/CU, 32 KB LDS, packed A and B.
// GEMM1 is launched as TWO M-half dispatches (instrumentation: puts the
// next-slowest kernel into the rocprof top-5 instead of 5x GEMM1 repeats).
template <bool OUT_BF16>
__global__ __launch_bounds__(256, 4) void lds_gemm_kernel(
    const unsigned short* __restrict__ Ap,
    const unsigned short* __restrict__ Bp,
    const float* __restrict__ bias,
    void* __restrict__ Cout,
    int M, int N, int K, int NB) {
    __shared__ unsigned short sA[16 * 512];   // [mt*2+s][512]  (s = k-subtile)
    __shared__ unsigned short sB[16 * 512];   // [nt*2+s][512]
    const int KB = K >> 5;                    // 32-wide k-tiles
    const int MB = M >> 7;
    const int id   = blockIdx.x;
    const int xcd  = id & 7;
    const int per  = id >> 3;
    const int MSTR = MB >> 3;
    const int byl  = per & 7;
    const int bx   = (per >> 3) % NB;
    const int pass = per / (8 * NB);
    const int by   = xcd * MSTR + pass * 8 + byl;

    const int w    = threadIdx.x >> 6;
    const int lane = threadIdx.x & 63;
    const int m0 = by * 128;
    const int n0 = bx * 128;
    const int wm = (w >> 1) * 64;
    const int wn = (w & 1) * 64;

    // staging: wave w owns LDS tiles {4w..4w+3} of A and of B.
    // LDS tile t -> (mt = t>>1, s = t&1); global k-tile = 2j + s.
    const unsigned short* gA[4];
    const unsigned short* gB[4];
    unsigned short* lA[4];
    unsigned short* lB[4];
    #pragma unroll
    for (int i = 0; i < 4; ++i) {
        const int t  = w * 4 + i;
        const int mt = t >> 1, s = t & 1;
        gA[i] = Ap + ((size_t)(by * 8 + mt) * KB + s) * 512 + lane * 8;
        gB[i] = Bp + ((size_t)(bx * 8 + mt) * KB + s) * 512 + lane * 8;
        lA[i] = sA + t * 512;
        lB[i] = sB + t * 512;
    }

    // fragment read pointers (linear in lane -> conflict-free ds_read_b128)
    const unsigned short* aP = sA + (wm >> 4) * 2 * 512 + lane * 8;
    const unsigned short* bP = sB + (wn >> 4) * 2 * 512 + lane * 8;

    const f32x4 zero4 = {0.f, 0.f, 0.f, 0.f};
    f32x4 acc[4][4];
    #pragma unroll
    for (int i = 0; i < 4; ++i)
        #pragma unroll
        for (int j = 0; j < 4; ++j) acc[i][j] = zero4;

    const int NIT = K >> 6;   // BK=64 iterations
    #pragma unroll 1
    for (int jt = 0; jt < NIT; ++jt) {
        #pragma unroll
        for (int i = 0; i < 4; ++i) {
            load_lds16(gA[i], lA[i]);
            load_lds16(gB[i], lB[i]);
        }
        #pragma unroll
        for (int i = 0; i < 4; ++i) { gA[i] += 1024; gB[i] += 1024; }
        __syncthreads();   // drains DMA (vmcnt) + aligns waves

        #pragma unroll
        for (int kk = 0; kk < 2; ++kk) {
            bf16x8 af[4], bfr[4];
            #pragma unroll
            for (int mi = 0; mi < 4; ++mi)
                af[mi]  = *(const bf16x8*)(aP + (mi * 2 + kk) * 512);
            #pragma unroll
            for (int ni = 0; ni < 4; ++ni)
                bfr[ni] = *(const bf16x8*)(bP + (ni * 2 + kk) * 512);
            #pragma unroll
            for (int mi = 0; mi < 4; ++mi)
                #pragma unroll
                for (int ni = 0; ni < 4; ++ni)
                    acc[mi][ni] = __builtin_amdgcn_mfma_f32_16x16x32_bf16(
                        af[mi], bfr[ni], acc[mi][ni], 0, 0, 0);
        }
        __syncthreads();   // LDS consumed before next staging overwrites
    }

    // epilogue: D row = (lane>>4)*4 + reg, col = lane&15
    const int fr = lane & 15;
    const int fq = lane >> 4;
    #pragma unroll
    for (int mi = 0; mi < 4; ++mi) {
        #pragma unroll
        for (int ni = 0; ni < 4; ++ni) {
            int row = m0 + wm + mi * 16 + fq * 4;
            int col = n0 + wn + ni * 16 + fr;
            float bb = bias[col];
            #pragma unroll
            for (int r = 0; r < 4; ++r) {
                float v = acc[mi][ni][r] + bb;
                if (OUT_BF16)
                    ((unsigned short*)Cout)[(size_t)(row + r) * N + col] = f2bf(v);
                else
                    ((float*)Cout)[(size_t)(row + r) * N + col] = v;
            }
        }
    }
}

// ---------------- per-token head-axis attention, MFMA, packed-fragment out ----------------
// Exact round-0 verified version. One wave per token; output written directly
// in packed-fragment layout so it feeds lds_gemm as A (no repack pass).
__global__ __launch_bounds__(256) void attn_mfma_kernel(
    const unsigned short* __restrict__ qkv,
    unsigned short* __restrict__ attP) {
    __shared__ char smem[4 * 3584];
    const int w    = threadIdx.x >> 6;
    const int lane = threadIdx.x & 63;
    const int m    = lane & 15;
    const int q    = lane >> 4;
    const int row  = blockIdx.x * 4 + w;
    unsigned short* sV = (unsigned short*)(smem + w * 3584);        // [16][72] bf16
    float*          sP = (float*)(smem + w * 3584 + 2304);          // [16][20] fp32

    const unsigned short* src = qkv + (size_t)row * 3072;

    bf16x8 aq0 = *(const bf16x8*)(src + m * 64 + q * 8);
    bf16x8 aq1 = *(const bf16x8*)(src + m * 64 + 32 + q * 8);
    bf16x8 bk0 = *(const bf16x8*)(src + 1024 + m * 64 + q * 8);
    bf16x8 bk1 = *(const bf16x8*)(src + 1024 + m * 64 + 32 + q * 8);

    #pragma unroll
    for (int t = 0; t < 2; ++t) {
        int G = t * 64 + lane;
        int r = G >> 3, p = G & 7;
        *(uint4*)(sV + r * 72 + p * 8) = *(const uint4*)(src + 2048 + G * 8);
    }

    f32x4 s = {0.f, 0.f, 0.f, 0.f};
    s = __builtin_amdgcn_mfma_f32_16x16x32_bf16(aq0, bk0, s, 0, 0, 0);
    s = __builtin_amdgcn_mfma_f32_16x16x32_bf16(aq1, bk1, s, 0, 0, 0);

    #pragma unroll
    for (int r = 0; r < 4; ++r) {
        float t0 = s[r] * 0.125f;
        float mx = t0;
        mx = fmaxf(mx, __shfl_xor(mx, 1));
        mx = fmaxf(mx, __shfl_xor(mx, 2));
        mx = fmaxf(mx, __shfl_xor(mx, 4));
        mx = fmaxf(mx, __shfl_xor(mx, 8));
        float e = __expf(t0 - mx);
        float su = e;
        su += __shfl_xor(su, 1);
        su += __shfl_xor(su, 2);
        su += __shfl_xor(su, 4);
        su += __shfl_xor(su, 8);
        sP[(q * 4 + r) * 20 + m] = e / su;
    }
    __syncthreads();

    const float* pr = sP + m * 20 + (q & 1) * 8;
    float4 pf0 = *(const float4*)(pr);
    float4 pf1 = *(const float4*)(pr + 4);
    const bool act = (q < 2);
    union { unsigned short u[8]; bf16x8 b; } pa;
    pa.u[0] = act ? f2bf(pf0.x) : 0;
    pa.u[1] = act ? f2bf(pf0.y) : 0;
    pa.u[2] = act ? f2bf(pf0.z) : 0;
    pa.u[3] = act ? f2bf(pf0.w) : 0;
    pa.u[4] = act ? f2bf(pf1.x) : 0;
    pa.u[5] = act ? f2bf(pf1.y) : 0;
    pa.u[6] = act ? f2bf(pf1.z) : 0;
    pa.u[7] = act ? f2bf(pf1.w) : 0;

    const unsigned short* vb = sV + (q & 1) * 8 * 72;
    const size_t tileBase = (size_t)(row >> 4) * 32 * 512;   // token's m-block row (KB=32)
    const int fr_tok = row & 15;
    #pragma unroll
    for (int c4 = 0; c4 < 4; ++c4) {
        union { unsigned short u[8]; bf16x8 b; } vf;
        #pragma unroll
        for (int j = 0; j < 8; ++j) vf.u[j] = vb[j * 72 + c4 * 16 + m];
        f32x4 o = {0.f, 0.f, 0.f, 0.f};
        o = __builtin_amdgcn_mfma_f32_16x16x32_bf16(pa.b, vf.b, o, 0, 0, 0);
        #pragma unroll
        for (int r = 0; r < 4; ++r) {
            int col = (q * 4 + r) * 64 + c4 * 16 + m;        // k index in [0,1024)
            size_t off = tileBase + (size_t)(col >> 5) * 512
                       + (((col >> 3) & 3) * 16 + fr_tok) * 8 + (col & 7);
            attP[off] = f2bf(o[r]);
        }
    }
}

extern "C" void kernel_launch(void* const* d_in, const int* in_sizes, int n_in,
                              void* d_out, int out_size, void* d_ws, size_t ws_size,
                              hipStream_t stream) {
    const float* x    = (const float*)d_in[0];
    const float* Wqkv = (const float*)d_in[1];
    const float* bqkv = (const float*)d_in[2];
    const float* Wout = (const float*)d_in[3];
    const float* bout = (const float*)d_in[4];
    float* out = (float*)d_out;

    // workspace: xp 32M | Wqkv_p 6M | Wout_p 2M | qkv 96M = ~136 MB
    char* ws = (char*)d_ws;
    unsigned short* xp   = (unsigned short*)ws;                 ws += (size_t)Mc * Kc * 2;
    unsigned short* Wqkp = (unsigned short*)ws;                 ws += (size_t)N1c * Kc * 2;
    unsigned short* Wop  = (unsigned short*)ws;                 ws += (size_t)Cc * Kc * 2;
    unsigned short* qkv  = (unsigned short*)ws;
    unsigned short* attP = xp;   // alias: xp dead after GEMM1 (packed [M/16][32] tiles)

    // 1) prep: x -> packed fragments; weights -> packed fragments (transposed)
    prep_kernel<<<8192 + 3072 + 1024, 256, 0, stream>>>(x, xp, Wqkv, Wqkp, Wout, Wop);

    // 2) qkv = x @ W_qkv + b_qkv (bf16 row-major out) — TWO M-half dispatches
    //    (instrumentation: ~52 us each so the next-slowest kernel surfaces in
    //     the rocprof top-5 instead of five GEMM1 repeats)
    constexpr int Mh = Mc / 2;
    const size_t Ahalf = (size_t)Mh * Kc;          // packed A shorts per half
    lds_gemm_kernel<true><<<(N1c / 128) * (Mh / 128), 256, 0, stream>>>(
        xp, Wqkp, bqkv, qkv, Mh, N1c, Kc, N1c / 128);
    lds_gemm_kernel<true><<<(N1c / 128) * (Mh / 128), 256, 0, stream>>>(
        xp + Ahalf, Wqkp, bqkv, qkv + (size_t)Mh * N1c, Mh, N1c, Kc, N1c / 128);

    // 3) head-axis attention per token (MFMA), writes packed-fragment A
    attn_mfma_kernel<<<Mc / 4, 256, 0, stream>>>(qkv, attP);

    // 4) out = att @ W_out + b_out (fp32 row-major out)
    lds_gemm_kernel<false><<<(Cc / 128) * (Mc / 128), 256, 0, stream>>>(
        attP, Wop, bout, out, Mc, Cc, Kc, Cc / 128);
}